// Round 3
// baseline (1309.647 us; speedup 1.0000x reference)
//
#include <hip/hip_runtime.h>
#include <hip/hip_bf16.h>

#define NN 50000
#define NE 1600000
#define DD 128
#define NPB 50                 // nodes per bucket
#define NBK 1000               // ceil(NN/NPB)
#define CHUNK 8192             // edges per histogram/scatter block
#define NCB 196                // ceil(NE/CHUNK)

typedef __attribute__((ext_vector_type(8))) unsigned short ushort8;

// ---- phase 1: per-bucket histogram --------------------------------------
__global__ __launch_bounds__(256) void hist_k(const int* __restrict__ ei,
                                              int* __restrict__ gcnt) {
    __shared__ int h[NBK];
    int t = threadIdx.x;
    for (int i = t; i < NBK; i += 256) h[i] = 0;
    __syncthreads();
    int e0 = blockIdx.x * CHUNK;
    for (int i = t; i < CHUNK; i += 256) {
        int e = e0 + i;
        if (e < NE) atomicAdd(&h[ei[NE + e] / NPB], 1);
    }
    __syncthreads();
    for (int i = t; i < NBK; i += 256)
        if (h[i]) atomicAdd(&gcnt[i], h[i]);
}

// ---- phase 2: exclusive scan of 1000 buckets (single block) -------------
__global__ __launch_bounds__(256) void scan_k(const int* __restrict__ gcnt,
                                              int* __restrict__ gbase,
                                              int* __restrict__ gcursor) {
    __shared__ int s[256];
    int t = threadIdx.x;
    int b4 = t * 4;
    int v[4], pre[4], sum = 0;
    #pragma unroll
    for (int k = 0; k < 4; ++k) {
        v[k] = (b4 + k < NBK) ? gcnt[b4 + k] : 0;
        pre[k] = sum;
        sum += v[k];
    }
    s[t] = sum;
    __syncthreads();
    #pragma unroll
    for (int o = 1; o < 256; o <<= 1) {
        int a = (t >= o) ? s[t - o] : 0;
        __syncthreads();
        s[t] += a;
        __syncthreads();
    }
    int excl = s[t] - sum;  // exclusive block prefix
    #pragma unroll
    for (int k = 0; k < 4; ++k) {
        int i = b4 + k;
        if (i <= NBK) {
            int val = excl + pre[k];
            gbase[i] = val;
            if (i < NBK) gcursor[i] = val;
        }
    }
}

// ---- phase 3: block-level counting-sort scatter into bucket order -------
__global__ __launch_bounds__(256) void scatter_k(const int* __restrict__ ei,
                                                 int* __restrict__ gcursor,
                                                 int* __restrict__ ebuf) {
    __shared__ int h[NBK];
    __shared__ int bse[NBK];
    int t = threadIdx.x;
    for (int i = t; i < NBK; i += 256) h[i] = 0;
    __syncthreads();
    int e0 = blockIdx.x * CHUNK;
    for (int i = t; i < CHUNK; i += 256) {
        int e = e0 + i;
        if (e < NE) atomicAdd(&h[ei[NE + e] / NPB], 1);
    }
    __syncthreads();
    for (int i = t; i < NBK; i += 256) {
        int c = h[i];
        bse[i] = c ? atomicAdd(&gcursor[i], c) : 0;
        h[i] = 0;  // reuse as running cursor
    }
    __syncthreads();
    for (int i = t; i < CHUNK; i += 256) {
        int e = e0 + i;
        if (e < NE) {
            int src = ei[e];
            int dst = ei[NE + e];
            int b = dst / NPB;
            int ofs = atomicAdd(&h[b], 1);
            ebuf[bse[b] + ofs] = (src << 6) | (dst - b * NPB);
        }
    }
}

// ---- phase 4: LDS-accumulated aggregation, one block per bucket ---------
// 256 threads = 2 halves x 128 features. Coalesced 512B gathers of x[src],
// conflict-free ds_add_f32 into 50x128 fp32 LDS tile, single mean write.
__global__ __launch_bounds__(256) void agg_k(const float* __restrict__ x,
                                             const int* __restrict__ ebuf,
                                             const int* __restrict__ gbase,
                                             float* __restrict__ mean) {
    __shared__ float acc[NPB * DD];  // 25.6 KB
    __shared__ int degL[NPB];
    int t = threadIdx.x;
    for (int i = t; i < NPB * DD; i += 256) acc[i] = 0.f;
    for (int i = t; i < NPB; i += 256) degL[i] = 0;
    __syncthreads();

    int b = blockIdx.x;
    int beg = gbase[b], end = gbase[b + 1];
    int pair = t >> 7;      // which half-block
    int j = t & 127;        // feature
    int i = beg;
    for (; i + 16 <= end; i += 16) {
        int e0 = i + pair * 8;
        int p[8];
        float v[8];
        #pragma unroll
        for (int u = 0; u < 8; ++u) p[u] = ebuf[e0 + u];
        #pragma unroll
        for (int u = 0; u < 8; ++u) v[u] = x[(size_t)(p[u] >> 6) * DD + j];
        #pragma unroll
        for (int u = 0; u < 8; ++u) atomicAdd(&acc[(p[u] & 63) * DD + j], v[u]);
        if (j == 0) {
            #pragma unroll
            for (int u = 0; u < 8; ++u) atomicAdd(&degL[p[u] & 63], 1);
        }
    }
    for (int e = i + pair; e < end; e += 2) {
        int p = ebuf[e];
        float v = x[(size_t)(p >> 6) * DD + j];
        atomicAdd(&acc[(p & 63) * DD + j], v);
        if (j == 0) atomicAdd(&degL[p & 63], 1);
    }
    __syncthreads();

    int n0 = b * NPB;
    for (int idx = t; idx < NPB * DD / 4; idx += 256) {
        int r = (idx * 4) >> 7;
        int c = (idx * 4) & 127;
        int n = n0 + r;
        if (n < NN) {
            float d = fmaxf((float)degL[r], 1.0f);
            float4 o = make_float4(acc[r * DD + c] / d, acc[r * DD + c + 1] / d,
                                   acc[r * DD + c + 2] / d, acc[r * DD + c + 3] / d);
            *(float4*)&mean[(size_t)n * DD + c] = o;
        }
    }
}

// ---- phase 5: fused epilogue out = mean @ W^T + x @ B^T ------------------
__global__ __launch_bounds__(256) void gemm_fused_k(const float* __restrict__ mean,
                                                    const float* __restrict__ x,
                                                    const float* __restrict__ W,
                                                    const float* __restrict__ Bm,
                                                    float* __restrict__ out) {
    __shared__ __hip_bfloat16 Wt[DD * DD];
    __shared__ __hip_bfloat16 Bt[DD * DD];
    const int tid = threadIdx.x;
    #pragma unroll
    for (int it = 0; it < 16; ++it) {
        int idx = it * 256 + tid;
        int j = idx >> 5;
        int k0 = (idx & 31) * 4;
        float4 w4 = ((const float4*)W)[idx];
        float4 b4 = ((const float4*)Bm)[idx];
        Wt[(k0 + 0) * DD + j] = __float2bfloat16(w4.x);
        Wt[(k0 + 1) * DD + j] = __float2bfloat16(w4.y);
        Wt[(k0 + 2) * DD + j] = __float2bfloat16(w4.z);
        Wt[(k0 + 3) * DD + j] = __float2bfloat16(w4.w);
        Bt[(k0 + 0) * DD + j] = __float2bfloat16(b4.x);
        Bt[(k0 + 1) * DD + j] = __float2bfloat16(b4.y);
        Bt[(k0 + 2) * DD + j] = __float2bfloat16(b4.z);
        Bt[(k0 + 3) * DD + j] = __float2bfloat16(b4.w);
    }
    __syncthreads();

    const int c = tid & 15;
    const int r = tid >> 4;
    const int row0 = blockIdx.x * 64 + r * 4;

    float acc[4][8];
    #pragma unroll
    for (int q = 0; q < 4; ++q)
        #pragma unroll
        for (int e = 0; e < 8; ++e) acc[q][e] = 0.f;

    for (int k0 = 0; k0 < DD; k0 += 4) {
        float4 m4[4], x4[4];
        #pragma unroll
        for (int q = 0; q < 4; ++q) {
            int row = min(row0 + q, NN - 1);
            m4[q] = *(const float4*)&mean[(size_t)row * DD + k0];
            x4[q] = *(const float4*)&x[(size_t)row * DD + k0];
        }
        #pragma unroll
        for (int u = 0; u < 4; ++u) {
            ushort8 wraw = *(const ushort8*)&Wt[(k0 + u) * DD + c * 8];
            ushort8 braw = *(const ushort8*)&Bt[(k0 + u) * DD + c * 8];
            float wv[8], bv[8];
            #pragma unroll
            for (int e = 0; e < 8; ++e) {
                wv[e] = __uint_as_float((unsigned)wraw[e] << 16);
                bv[e] = __uint_as_float((unsigned)braw[e] << 16);
            }
            #pragma unroll
            for (int q = 0; q < 4; ++q) {
                float mq = (u == 0) ? m4[q].x : (u == 1) ? m4[q].y : (u == 2) ? m4[q].z : m4[q].w;
                float xq = (u == 0) ? x4[q].x : (u == 1) ? x4[q].y : (u == 2) ? x4[q].z : x4[q].w;
                #pragma unroll
                for (int e = 0; e < 8; ++e)
                    acc[q][e] = fmaf(mq, wv[e], fmaf(xq, bv[e], acc[q][e]));
            }
        }
    }

    #pragma unroll
    for (int q = 0; q < 4; ++q) {
        int row = row0 + q;
        if (row < NN) {
            float4 lo = make_float4(acc[q][0], acc[q][1], acc[q][2], acc[q][3]);
            float4 hi = make_float4(acc[q][4], acc[q][5], acc[q][6], acc[q][7]);
            float4* p = (float4*)&out[(size_t)row * DD + c * 8];
            p[0] = lo;
            p[1] = hi;
        }
    }
}

extern "C" void kernel_launch(void* const* d_in, const int* in_sizes, int n_in,
                              void* d_out, int out_size, void* d_ws, size_t ws_size,
                              hipStream_t stream) {
    const float* x  = (const float*)d_in[0];
    const int*   ei = (const int*)d_in[1];   // [2, NE] int32
    const float* W  = (const float*)d_in[2];
    const float* Bm = (const float*)d_in[3];
    float* out = (float*)d_out;

    float* mean   = (float*)d_ws;                     // NN*DD
    int* ebuf     = (int*)(mean + (size_t)NN * DD);   // NE
    int* gcnt     = ebuf + NE;                        // NBK
    int* gbase    = gcnt + NBK;                       // NBK+1
    int* gcursor  = gbase + NBK + 1;                  // NBK

    hipMemsetAsync(gcnt, 0, NBK * sizeof(int), stream);
    hist_k<<<NCB, 256, 0, stream>>>(ei, gcnt);
    scan_k<<<1, 256, 0, stream>>>(gcnt, gbase, gcursor);
    scatter_k<<<NCB, 256, 0, stream>>>(ei, gcursor, ebuf);
    agg_k<<<NBK, 256, 0, stream>>>(x, ebuf, gbase, mean);
    gemm_fused_k<<<(NN + 63) / 64, 256, 0, stream>>>(mean, x, W, Bm, out);
}

// Round 4
// 336.752 us; speedup vs baseline: 3.8891x; 3.8891x over previous
//
#include <hip/hip_runtime.h>
#include <hip/hip_bf16.h>

#define NN 50000
#define NE 1600000
#define DD 128
#define NPB 50                 // nodes per bucket
#define NBK 1000               // NN / NPB
#define CHUNK 8192             // edges per histogram/scatter block
#define NCB 196                // ceil(NE/CHUNK)
#define MAXB 2304              // max edges per bucket (mean 1600, sigma 40 -> 17 sigma)

typedef __attribute__((ext_vector_type(8))) unsigned short ushort8;

// ---- phase 1: per-bucket histogram --------------------------------------
__global__ __launch_bounds__(256) void hist_k(const int* __restrict__ ei,
                                              int* __restrict__ gcnt) {
    __shared__ int h[NBK];
    int t = threadIdx.x;
    for (int i = t; i < NBK; i += 256) h[i] = 0;
    __syncthreads();
    int e0 = blockIdx.x * CHUNK;
    for (int i = t; i < CHUNK; i += 256) {
        int e = e0 + i;
        if (e < NE) atomicAdd(&h[ei[NE + e] / NPB], 1);
    }
    __syncthreads();
    for (int i = t; i < NBK; i += 256)
        if (h[i]) atomicAdd(&gcnt[i], h[i]);
}

// ---- phase 2: exclusive scan of 1000 buckets (single block) -------------
__global__ __launch_bounds__(256) void scan_k(const int* __restrict__ gcnt,
                                              int* __restrict__ gbase,
                                              int* __restrict__ gcursor) {
    __shared__ int s[256];
    int t = threadIdx.x;
    int b4 = t * 4;
    int v[4], pre[4], sum = 0;
    #pragma unroll
    for (int k = 0; k < 4; ++k) {
        v[k] = (b4 + k < NBK) ? gcnt[b4 + k] : 0;
        pre[k] = sum;
        sum += v[k];
    }
    s[t] = sum;
    __syncthreads();
    #pragma unroll
    for (int o = 1; o < 256; o <<= 1) {
        int a = (t >= o) ? s[t - o] : 0;
        __syncthreads();
        s[t] += a;
        __syncthreads();
    }
    int excl = s[t] - sum;
    #pragma unroll
    for (int k = 0; k < 4; ++k) {
        int i = b4 + k;
        if (i <= NBK) {
            int val = excl + pre[k];
            gbase[i] = val;
            if (i < NBK) gcursor[i] = val;
        }
    }
}

// ---- phase 3: block-level counting-sort scatter into bucket order -------
__global__ __launch_bounds__(256) void scatter_k(const int* __restrict__ ei,
                                                 int* __restrict__ gcursor,
                                                 int* __restrict__ ebuf) {
    __shared__ int h[NBK];
    __shared__ int bse[NBK];
    int t = threadIdx.x;
    for (int i = t; i < NBK; i += 256) h[i] = 0;
    __syncthreads();
    int e0 = blockIdx.x * CHUNK;
    for (int i = t; i < CHUNK; i += 256) {
        int e = e0 + i;
        if (e < NE) atomicAdd(&h[ei[NE + e] / NPB], 1);
    }
    __syncthreads();
    for (int i = t; i < NBK; i += 256) {
        int c = h[i];
        bse[i] = c ? atomicAdd(&gcursor[i], c) : 0;
        h[i] = 0;  // reuse as running cursor
    }
    __syncthreads();
    for (int i = t; i < CHUNK; i += 256) {
        int e = e0 + i;
        if (e < NE) {
            int src = ei[e];
            int dst = ei[NE + e];
            int b = dst / NPB;
            int ofs = atomicAdd(&h[b], 1);
            ebuf[bse[b] + ofs] = (src << 6) | (dst - b * NPB);
        }
    }
}

// ---- phase 4: in-LDS per-bucket counting sort by node -------------------
// Stages the bucket run in LDS, sorts by dstLocal, rewrites ebuf in place
// with plain src ids (node-grouped), and emits per-node offsets.
__global__ __launch_bounds__(256) void sort_k(int* __restrict__ ebuf,
                                              const int* __restrict__ gbase,
                                              int* __restrict__ offs) {
    __shared__ int stg[MAXB];
    __shared__ int cnt[NPB];
    __shared__ int cur[NPB];
    int b = blockIdx.x, t = threadIdx.x;
    int beg = gbase[b], end = gbase[b + 1];
    int n = end - beg;
    for (int i = t; i < n; i += 256) stg[i] = ebuf[beg + i];
    if (t < NPB) cnt[t] = 0;
    __syncthreads();
    for (int i = t; i < n; i += 256) atomicAdd(&cnt[stg[i] & 63], 1);
    __syncthreads();
    if (t < 64) {
        int v = (t < NPB) ? cnt[t] : 0;
        int s = v;
        #pragma unroll
        for (int o = 1; o < 64; o <<= 1) {
            int u = __shfl_up(s, o);
            if (t >= o) s += u;
        }
        int excl = s - v;
        if (t < NPB) {
            cur[t] = excl;
            offs[b * NPB + t] = beg + excl;
        }
    }
    if (b == NBK - 1 && t == 0) offs[NN] = NE;
    __syncthreads();
    for (int i = t; i < n; i += 256) {
        int w = stg[i];
        int pos = atomicAdd(&cur[w & 63], 1);
        ebuf[beg + pos] = w >> 6;  // store plain src, node-grouped
    }
}

// ---- phase 5: aggregation, one wave per node ----------------------------
// lane = 2 features (float2); indices shfl-broadcast; 4-deep ILP; no atomics.
__global__ __launch_bounds__(256) void agg_k(const float* __restrict__ x,
                                             const int* __restrict__ ebuf,
                                             const int* __restrict__ offs,
                                             float* __restrict__ mean) {
    int nd = blockIdx.x * 4 + (threadIdx.x >> 6);
    int lane = threadIdx.x & 63;
    int beg = offs[nd], end = offs[nd + 1];
    const float2* __restrict__ xp = (const float2*)x;  // row stride 64
    float2 a0 = {0.f, 0.f}, a1 = {0.f, 0.f}, a2 = {0.f, 0.f}, a3 = {0.f, 0.f};
    for (int base = beg; base < end; base += 64) {
        int m = min(64, end - base);
        int s = (lane < m) ? ebuf[base + lane] : 0;
        int i = 0;
        for (; i + 4 <= m; i += 4) {
            int s0 = __shfl(s, i);
            int s1 = __shfl(s, i + 1);
            int s2 = __shfl(s, i + 2);
            int s3 = __shfl(s, i + 3);
            float2 v0 = xp[(size_t)s0 * 64 + lane];
            float2 v1 = xp[(size_t)s1 * 64 + lane];
            float2 v2 = xp[(size_t)s2 * 64 + lane];
            float2 v3 = xp[(size_t)s3 * 64 + lane];
            a0.x += v0.x; a0.y += v0.y;
            a1.x += v1.x; a1.y += v1.y;
            a2.x += v2.x; a2.y += v2.y;
            a3.x += v3.x; a3.y += v3.y;
        }
        for (; i < m; ++i) {
            int s0 = __shfl(s, i);
            float2 v0 = xp[(size_t)s0 * 64 + lane];
            a0.x += v0.x; a0.y += v0.y;
        }
    }
    float inv = 1.0f / fmaxf((float)(end - beg), 1.0f);
    float2 o;
    o.x = (a0.x + a1.x + a2.x + a3.x) * inv;
    o.y = (a0.y + a1.y + a2.y + a3.y) * inv;
    ((float2*)mean)[(size_t)nd * 64 + lane] = o;
}

// ---- phase 6: fused epilogue out = mean @ W^T + x @ B^T ------------------
__global__ __launch_bounds__(256) void gemm_fused_k(const float* __restrict__ mean,
                                                    const float* __restrict__ x,
                                                    const float* __restrict__ W,
                                                    const float* __restrict__ Bm,
                                                    float* __restrict__ out) {
    __shared__ __hip_bfloat16 Wt[DD * DD];
    __shared__ __hip_bfloat16 Bt[DD * DD];
    const int tid = threadIdx.x;
    #pragma unroll
    for (int it = 0; it < 16; ++it) {
        int idx = it * 256 + tid;
        int j = idx >> 5;
        int k0 = (idx & 31) * 4;
        float4 w4 = ((const float4*)W)[idx];
        float4 b4 = ((const float4*)Bm)[idx];
        Wt[(k0 + 0) * DD + j] = __float2bfloat16(w4.x);
        Wt[(k0 + 1) * DD + j] = __float2bfloat16(w4.y);
        Wt[(k0 + 2) * DD + j] = __float2bfloat16(w4.z);
        Wt[(k0 + 3) * DD + j] = __float2bfloat16(w4.w);
        Bt[(k0 + 0) * DD + j] = __float2bfloat16(b4.x);
        Bt[(k0 + 1) * DD + j] = __float2bfloat16(b4.y);
        Bt[(k0 + 2) * DD + j] = __float2bfloat16(b4.z);
        Bt[(k0 + 3) * DD + j] = __float2bfloat16(b4.w);
    }
    __syncthreads();

    const int c = tid & 15;
    const int r = tid >> 4;
    const int row0 = blockIdx.x * 64 + r * 4;

    float acc[4][8];
    #pragma unroll
    for (int q = 0; q < 4; ++q)
        #pragma unroll
        for (int e = 0; e < 8; ++e) acc[q][e] = 0.f;

    for (int k0 = 0; k0 < DD; k0 += 4) {
        float4 m4[4], x4[4];
        #pragma unroll
        for (int q = 0; q < 4; ++q) {
            int row = min(row0 + q, NN - 1);
            m4[q] = *(const float4*)&mean[(size_t)row * DD + k0];
            x4[q] = *(const float4*)&x[(size_t)row * DD + k0];
        }
        #pragma unroll
        for (int u = 0; u < 4; ++u) {
            ushort8 wraw = *(const ushort8*)&Wt[(k0 + u) * DD + c * 8];
            ushort8 braw = *(const ushort8*)&Bt[(k0 + u) * DD + c * 8];
            float wv[8], bv[8];
            #pragma unroll
            for (int e = 0; e < 8; ++e) {
                wv[e] = __uint_as_float((unsigned)wraw[e] << 16);
                bv[e] = __uint_as_float((unsigned)braw[e] << 16);
            }
            #pragma unroll
            for (int q = 0; q < 4; ++q) {
                float mq = (u == 0) ? m4[q].x : (u == 1) ? m4[q].y : (u == 2) ? m4[q].z : m4[q].w;
                float xq = (u == 0) ? x4[q].x : (u == 1) ? x4[q].y : (u == 2) ? x4[q].z : x4[q].w;
                #pragma unroll
                for (int e = 0; e < 8; ++e)
                    acc[q][e] = fmaf(mq, wv[e], fmaf(xq, bv[e], acc[q][e]));
            }
        }
    }

    #pragma unroll
    for (int q = 0; q < 4; ++q) {
        int row = row0 + q;
        if (row < NN) {
            float4 lo = make_float4(acc[q][0], acc[q][1], acc[q][2], acc[q][3]);
            float4 hi = make_float4(acc[q][4], acc[q][5], acc[q][6], acc[q][7]);
            float4* p = (float4*)&out[(size_t)row * DD + c * 8];
            p[0] = lo;
            p[1] = hi;
        }
    }
}

extern "C" void kernel_launch(void* const* d_in, const int* in_sizes, int n_in,
                              void* d_out, int out_size, void* d_ws, size_t ws_size,
                              hipStream_t stream) {
    const float* x  = (const float*)d_in[0];
    const int*   ei = (const int*)d_in[1];   // [2, NE] int32
    const float* W  = (const float*)d_in[2];
    const float* Bm = (const float*)d_in[3];
    float* out = (float*)d_out;

    float* mean   = (float*)d_ws;                     // NN*DD
    int* ebuf     = (int*)(mean + (size_t)NN * DD);   // NE
    int* gcnt     = ebuf + NE;                        // NBK
    int* gbase    = gcnt + NBK;                       // NBK+1
    int* gcursor  = gbase + NBK + 1;                  // NBK
    int* offs     = gcursor + NBK;                    // NN+1

    hipMemsetAsync(gcnt, 0, NBK * sizeof(int), stream);
    hist_k<<<NCB, 256, 0, stream>>>(ei, gcnt);
    scan_k<<<1, 256, 0, stream>>>(gcnt, gbase, gcursor);
    scatter_k<<<NCB, 256, 0, stream>>>(ei, gcursor, ebuf);
    sort_k<<<NBK, 256, 0, stream>>>(ebuf, gbase, offs);
    agg_k<<<NN / 4, 256, 0, stream>>>(x, ebuf, offs, mean);
    gemm_fused_k<<<(NN + 63) / 64, 256, 0, stream>>>(mean, x, W, Bm, out);
}

// Round 5
// 256.567 us; speedup vs baseline: 5.1045x; 1.3125x over previous
//
#include <hip/hip_runtime.h>
#include <hip/hip_bf16.h>

#define NN 50000
#define NE 1600000
#define DD 128
#define NPB 50                 // nodes per bucket
#define NBK 1000               // NN / NPB
#define CHUNK 8192             // edges per histogram/scatter block
#define NCB 196                // ceil(NE/CHUNK)
#define MAXB 2304              // max edges per bucket (mean 1600 -> 17 sigma headroom)
#define WS 136                 // LDS row stride (bf16 elems), padded: balanced banks

typedef __attribute__((ext_vector_type(8))) short short8;
typedef __attribute__((ext_vector_type(4))) float f32x4;

__device__ inline unsigned short to_bf16(float v) {
    __hip_bfloat16 h = __float2bfloat16(v);
    return __builtin_bit_cast(unsigned short, h);
}

// ---- phase 1: per-bucket histogram --------------------------------------
__global__ __launch_bounds__(256) void hist_k(const int* __restrict__ ei,
                                              int* __restrict__ gcnt) {
    __shared__ int h[NBK];
    int t = threadIdx.x;
    for (int i = t; i < NBK; i += 256) h[i] = 0;
    __syncthreads();
    int e0 = blockIdx.x * CHUNK;
    for (int i = t; i < CHUNK; i += 256) {
        int e = e0 + i;
        if (e < NE) atomicAdd(&h[ei[NE + e] / NPB], 1);
    }
    __syncthreads();
    for (int i = t; i < NBK; i += 256)
        if (h[i]) atomicAdd(&gcnt[i], h[i]);
}

// ---- phase 2: exclusive scan of 1000 buckets (single block) -------------
__global__ __launch_bounds__(256) void scan_k(const int* __restrict__ gcnt,
                                              int* __restrict__ gbase,
                                              int* __restrict__ gcursor) {
    __shared__ int s[256];
    int t = threadIdx.x;
    int b4 = t * 4;
    int v[4], pre[4], sum = 0;
    #pragma unroll
    for (int k = 0; k < 4; ++k) {
        v[k] = (b4 + k < NBK) ? gcnt[b4 + k] : 0;
        pre[k] = sum;
        sum += v[k];
    }
    s[t] = sum;
    __syncthreads();
    #pragma unroll
    for (int o = 1; o < 256; o <<= 1) {
        int a = (t >= o) ? s[t - o] : 0;
        __syncthreads();
        s[t] += a;
        __syncthreads();
    }
    int excl = s[t] - sum;
    #pragma unroll
    for (int k = 0; k < 4; ++k) {
        int i = b4 + k;
        if (i <= NBK) {
            int val = excl + pre[k];
            gbase[i] = val;
            if (i < NBK) gcursor[i] = val;
        }
    }
}

// ---- phase 3: block-level counting-sort scatter into bucket order -------
__global__ __launch_bounds__(256) void scatter_k(const int* __restrict__ ei,
                                                 int* __restrict__ gcursor,
                                                 int* __restrict__ ebuf) {
    __shared__ int h[NBK];
    __shared__ int bse[NBK];
    int t = threadIdx.x;
    for (int i = t; i < NBK; i += 256) h[i] = 0;
    __syncthreads();
    int e0 = blockIdx.x * CHUNK;
    for (int i = t; i < CHUNK; i += 256) {
        int e = e0 + i;
        if (e < NE) atomicAdd(&h[ei[NE + e] / NPB], 1);
    }
    __syncthreads();
    for (int i = t; i < NBK; i += 256) {
        int c = h[i];
        bse[i] = c ? atomicAdd(&gcursor[i], c) : 0;
        h[i] = 0;  // reuse as running cursor
    }
    __syncthreads();
    for (int i = t; i < CHUNK; i += 256) {
        int e = e0 + i;
        if (e < NE) {
            int src = ei[e];
            int dst = ei[NE + e];
            int b = dst / NPB;
            int ofs = atomicAdd(&h[b], 1);
            ebuf[bse[b] + ofs] = (src << 6) | (dst - b * NPB);
        }
    }
}

// ---- phase 4: in-LDS per-bucket counting sort by node -------------------
__global__ __launch_bounds__(256) void sort_k(int* __restrict__ ebuf,
                                              const int* __restrict__ gbase,
                                              int* __restrict__ offs) {
    __shared__ int stg[MAXB];
    __shared__ int cnt[NPB];
    __shared__ int cur[NPB];
    int b = blockIdx.x, t = threadIdx.x;
    int beg = gbase[b], end = gbase[b + 1];
    int n = end - beg;
    for (int i = t; i < n; i += 256) stg[i] = ebuf[beg + i];
    if (t < NPB) cnt[t] = 0;
    __syncthreads();
    for (int i = t; i < n; i += 256) atomicAdd(&cnt[stg[i] & 63], 1);
    __syncthreads();
    if (t < 64) {
        int v = (t < NPB) ? cnt[t] : 0;
        int s = v;
        #pragma unroll
        for (int o = 1; o < 64; o <<= 1) {
            int u = __shfl_up(s, o);
            if (t >= o) s += u;
        }
        int excl = s - v;
        if (t < NPB) {
            cur[t] = excl;
            offs[b * NPB + t] = beg + excl;
        }
    }
    if (b == NBK - 1 && t == 0) offs[NN] = NE;
    __syncthreads();
    for (int i = t; i < n; i += 256) {
        int w = stg[i];
        int pos = atomicAdd(&cur[w & 63], 1);
        ebuf[beg + pos] = w >> 6;  // store plain src, node-grouped
    }
}

// ---- phase 5: aggregation, one wave per node ----------------------------
__global__ __launch_bounds__(256) void agg_k(const float* __restrict__ x,
                                             const int* __restrict__ ebuf,
                                             const int* __restrict__ offs,
                                             float* __restrict__ mean) {
    int nd = blockIdx.x * 4 + (threadIdx.x >> 6);
    int lane = threadIdx.x & 63;
    int beg = offs[nd], end = offs[nd + 1];
    const float2* __restrict__ xp = (const float2*)x;  // row stride 64
    float2 a0 = {0.f, 0.f}, a1 = {0.f, 0.f}, a2 = {0.f, 0.f}, a3 = {0.f, 0.f};
    for (int base = beg; base < end; base += 64) {
        int m = min(64, end - base);
        int s = (lane < m) ? ebuf[base + lane] : 0;
        int i = 0;
        for (; i + 4 <= m; i += 4) {
            int s0 = __shfl(s, i);
            int s1 = __shfl(s, i + 1);
            int s2 = __shfl(s, i + 2);
            int s3 = __shfl(s, i + 3);
            float2 v0 = xp[(size_t)s0 * 64 + lane];
            float2 v1 = xp[(size_t)s1 * 64 + lane];
            float2 v2 = xp[(size_t)s2 * 64 + lane];
            float2 v3 = xp[(size_t)s3 * 64 + lane];
            a0.x += v0.x; a0.y += v0.y;
            a1.x += v1.x; a1.y += v1.y;
            a2.x += v2.x; a2.y += v2.y;
            a3.x += v3.x; a3.y += v3.y;
        }
        for (; i < m; ++i) {
            int s0 = __shfl(s, i);
            float2 v0 = xp[(size_t)s0 * 64 + lane];
            a0.x += v0.x; a0.y += v0.y;
        }
    }
    float inv = 1.0f / fmaxf((float)(end - beg), 1.0f);
    float2 o;
    o.x = (a0.x + a1.x + a2.x + a3.x) * inv;
    o.y = (a0.y + a1.y + a2.y + a3.y) * inv;
    ((float2*)mean)[(size_t)nd * 64 + lane] = o;
}

// ---- phase 6: MFMA epilogue out = mean @ W^T + x @ B^T -------------------
// 16x16x32 bf16 MFMA; W,B bf16 in LDS [n][k] stride WS=136 (balanced banks).
// A (mean,x) split hi+lo bf16 for ~fp32 accuracy. One wave = 16 rows x 128 cols.
__global__ __launch_bounds__(256) void gemm_mfma_k(const float* __restrict__ mean,
                                                   const float* __restrict__ x,
                                                   const float* __restrict__ W,
                                                   const float* __restrict__ Bm,
                                                   float* __restrict__ out) {
    __shared__ unsigned short Wt[DD * WS];
    __shared__ unsigned short Bt[DD * WS];
    const int tid = threadIdx.x;
    #pragma unroll
    for (int it = 0; it < 16; ++it) {
        int idx = it * 256 + tid;          // float4 index into 128x128
        int n = idx >> 5;                  // W row (output col)
        int k0 = (idx & 31) * 4;           // k
        float4 w4 = ((const float4*)W)[idx];
        float4 b4 = ((const float4*)Bm)[idx];
        ushort4 wp, bp;
        wp.x = to_bf16(w4.x); wp.y = to_bf16(w4.y); wp.z = to_bf16(w4.z); wp.w = to_bf16(w4.w);
        bp.x = to_bf16(b4.x); bp.y = to_bf16(b4.y); bp.z = to_bf16(b4.z); bp.w = to_bf16(b4.w);
        *(ushort4*)&Wt[n * WS + k0] = wp;   // 8B store, 2 lanes/bank = free
        *(ushort4*)&Bt[n * WS + k0] = bp;
    }
    __syncthreads();

    const int wave = tid >> 6;
    const int lane = tid & 63;
    const int m = lane & 15;
    const int quad = lane >> 4;
    const int rowA = min(blockIdx.x * 64 + wave * 16 + m, NN - 1);  // a-frag row

    f32x4 acc[8];
    #pragma unroll
    for (int nt = 0; nt < 8; ++nt) acc[nt] = (f32x4){0.f, 0.f, 0.f, 0.f};

    #pragma unroll
    for (int t = 0; t < 4; ++t) {
        const int k8 = t * 32 + quad * 8;  // this lane's 8-elem k chunk
        float av[8], xv[8];
        {
            const float4* mp = (const float4*)&mean[(size_t)rowA * DD + k8];
            const float4* xq = (const float4*)&x[(size_t)rowA * DD + k8];
            float4 a0 = mp[0], a1 = mp[1], b0 = xq[0], b1 = xq[1];
            av[0] = a0.x; av[1] = a0.y; av[2] = a0.z; av[3] = a0.w;
            av[4] = a1.x; av[5] = a1.y; av[6] = a1.z; av[7] = a1.w;
            xv[0] = b0.x; xv[1] = b0.y; xv[2] = b0.z; xv[3] = b0.w;
            xv[4] = b1.x; xv[5] = b1.y; xv[6] = b1.z; xv[7] = b1.w;
        }
        short8 mh, ml, xh, xl;
        #pragma unroll
        for (int j = 0; j < 8; ++j) {
            unsigned short h = to_bf16(av[j]);
            mh[j] = (short)h;
            ml[j] = (short)to_bf16(av[j] - __uint_as_float((unsigned)h << 16));
            unsigned short g = to_bf16(xv[j]);
            xh[j] = (short)g;
            xl[j] = (short)to_bf16(xv[j] - __uint_as_float((unsigned)g << 16));
        }
        #pragma unroll
        for (int nt = 0; nt < 8; ++nt) {
            int nrow = nt * 16 + m;
            short8 wf = *(const short8*)&Wt[nrow * WS + k8];
            short8 bf = *(const short8*)&Bt[nrow * WS + k8];
            acc[nt] = __builtin_amdgcn_mfma_f32_16x16x32_bf16(ml, wf, acc[nt], 0, 0, 0);
            acc[nt] = __builtin_amdgcn_mfma_f32_16x16x32_bf16(xl, bf, acc[nt], 0, 0, 0);
            acc[nt] = __builtin_amdgcn_mfma_f32_16x16x32_bf16(mh, wf, acc[nt], 0, 0, 0);
            acc[nt] = __builtin_amdgcn_mfma_f32_16x16x32_bf16(xh, bf, acc[nt], 0, 0, 0);
        }
    }

    // C/D layout: col = lane&15, row = quad*4 + reg (verified m89/m91)
    const int rowD0 = blockIdx.x * 64 + wave * 16 + quad * 4;
    #pragma unroll
    for (int nt = 0; nt < 8; ++nt) {
        #pragma unroll
        for (int r = 0; r < 4; ++r) {
            int row = rowD0 + r;
            if (row < NN) out[(size_t)row * DD + nt * 16 + m] = acc[nt][r];
        }
    }
}

extern "C" void kernel_launch(void* const* d_in, const int* in_sizes, int n_in,
                              void* d_out, int out_size, void* d_ws, size_t ws_size,
                              hipStream_t stream) {
    const float* x  = (const float*)d_in[0];
    const int*   ei = (const int*)d_in[1];   // [2, NE] int32
    const float* W  = (const float*)d_in[2];
    const float* Bm = (const float*)d_in[3];
    float* out = (float*)d_out;

    float* mean   = (float*)d_ws;                     // NN*DD
    int* ebuf     = (int*)(mean + (size_t)NN * DD);   // NE
    int* gcnt     = ebuf + NE;                        // NBK
    int* gbase    = gcnt + NBK;                       // NBK+1
    int* gcursor  = gbase + NBK + 1;                  // NBK
    int* offs     = gcursor + NBK;                    // NN+1

    hipMemsetAsync(gcnt, 0, NBK * sizeof(int), stream);
    hist_k<<<NCB, 256, 0, stream>>>(ei, gcnt);
    scan_k<<<1, 256, 0, stream>>>(gcnt, gbase, gcursor);
    scatter_k<<<NCB, 256, 0, stream>>>(ei, gcursor, ebuf);
    sort_k<<<NBK, 256, 0, stream>>>(ebuf, gbase, offs);
    agg_k<<<NN / 4, 256, 0, stream>>>(x, ebuf, offs, mean);
    gemm_mfma_k<<<(NN + 63) / 64, 256, 0, stream>>>(mean, x, W, Bm, out);
}

// Round 6
// 212.686 us; speedup vs baseline: 6.1577x; 1.2063x over previous
//
#include <hip/hip_runtime.h>
#include <hip/hip_bf16.h>

#define NN 50000
#define NE 1600000
#define DD 128
#define NPB 64                 // nodes per bucket (dst>>6)
#define NBK 782                // ceil(NN/64)
#define CHUNK 8192             // edges per histogram/scatter block
#define NCB 196                // ceil(NE/CHUNK)
#define MAXB 2560              // max edges/bucket (mean 2048, sigma 45 -> +11 sigma)
#define WS 136                 // gemm LDS row stride (bf16 elems): balanced banks

typedef __attribute__((ext_vector_type(8))) short short8;
typedef __attribute__((ext_vector_type(4))) float f32x4;

__device__ inline unsigned short to_bf16(float v) {
    __hip_bfloat16 h = __float2bfloat16(v);
    return __builtin_bit_cast(unsigned short, h);
}

// ---- phase 1: per-bucket histogram + x -> packed bf16 -------------------
__global__ __launch_bounds__(256) void hist_k(const int* __restrict__ ei,
                                              int* __restrict__ gcnt,
                                              const float* __restrict__ x,
                                              unsigned int* __restrict__ xb) {
    __shared__ int h[NBK];
    int t = threadIdx.x;
    for (int i = t; i < NBK; i += 256) h[i] = 0;
    __syncthreads();
    int e0 = blockIdx.x * CHUNK;
    for (int i = t; i < CHUNK; i += 256) {
        int e = e0 + i;
        if (e < NE) atomicAdd(&h[ei[NE + e] >> 6], 1);
    }
    // independent: convert x (fp32) -> xb (packed 2x bf16 per uint)
    int gid = blockIdx.x * 256 + t;
    const int total4 = NN * DD / 4;  // 1.6M float4
    for (int i = gid; i < total4; i += NCB * 256) {
        float4 v = ((const float4*)x)[i];
        unsigned int lo = (unsigned)to_bf16(v.x) | ((unsigned)to_bf16(v.y) << 16);
        unsigned int hi = (unsigned)to_bf16(v.z) | ((unsigned)to_bf16(v.w) << 16);
        ((uint2*)xb)[i] = make_uint2(lo, hi);
    }
    __syncthreads();
    for (int i = t; i < NBK; i += 256)
        if (h[i]) atomicAdd(&gcnt[i], h[i]);
}

// ---- phase 2: exclusive scan of NBK buckets (single block) --------------
__global__ __launch_bounds__(256) void scan_k(const int* __restrict__ gcnt,
                                              int* __restrict__ gbase,
                                              int* __restrict__ gcursor) {
    __shared__ int s[256];
    int t = threadIdx.x;
    int b4 = t * 4;
    int v[4], pre[4], sum = 0;
    #pragma unroll
    for (int k = 0; k < 4; ++k) {
        v[k] = (b4 + k < NBK) ? gcnt[b4 + k] : 0;
        pre[k] = sum;
        sum += v[k];
    }
    s[t] = sum;
    __syncthreads();
    #pragma unroll
    for (int o = 1; o < 256; o <<= 1) {
        int a = (t >= o) ? s[t - o] : 0;
        __syncthreads();
        s[t] += a;
        __syncthreads();
    }
    int excl = s[t] - sum;
    #pragma unroll
    for (int k = 0; k < 4; ++k) {
        int i = b4 + k;
        if (i <= NBK) {
            int val = excl + pre[k];
            gbase[i] = val;
            if (i < NBK) gcursor[i] = val;
        }
    }
}

// ---- phase 3: block-level counting-sort scatter into bucket order -------
__global__ __launch_bounds__(256) void scatter_k(const int* __restrict__ ei,
                                                 int* __restrict__ gcursor,
                                                 int* __restrict__ ebuf) {
    __shared__ int h[NBK];
    __shared__ int bse[NBK];
    int t = threadIdx.x;
    for (int i = t; i < NBK; i += 256) h[i] = 0;
    __syncthreads();
    int e0 = blockIdx.x * CHUNK;
    for (int i = t; i < CHUNK; i += 256) {
        int e = e0 + i;
        if (e < NE) atomicAdd(&h[ei[NE + e] >> 6], 1);
    }
    __syncthreads();
    for (int i = t; i < NBK; i += 256) {
        int c = h[i];
        bse[i] = c ? atomicAdd(&gcursor[i], c) : 0;
        h[i] = 0;  // reuse as running cursor
    }
    __syncthreads();
    for (int i = t; i < CHUNK; i += 256) {
        int e = e0 + i;
        if (e < NE) {
            int src = ei[e];
            int dst = ei[NE + e];
            int b = dst >> 6;
            int ofs = atomicAdd(&h[b], 1);
            ebuf[bse[b] + ofs] = (src << 6) | (dst & 63);
        }
    }
}

// ---- phase 4: per-bucket sort + aggregation (merged) --------------------
// 1024 threads: stage bucket, LDS counting sort by dstLocal -> srt (ushort),
// then 16 waves x 4 nodes each: register-accumulate bf16 gathers from xb,
// write mean as packed bf16.
__global__ __launch_bounds__(1024) void sortagg_k(const unsigned int* __restrict__ xb,
                                                  const int* __restrict__ ebuf,
                                                  const int* __restrict__ gbase,
                                                  unsigned int* __restrict__ meanb) {
    __shared__ int stg[MAXB];
    __shared__ unsigned short srt[MAXB];
    __shared__ int cnt[NPB], cur[NPB], off[NPB + 1];
    int b = blockIdx.x, t = threadIdx.x;
    int beg = gbase[b], end = gbase[b + 1];
    int n = end - beg;
    for (int i = t; i < n; i += 1024) stg[i] = ebuf[beg + i];
    if (t < NPB) cnt[t] = 0;
    __syncthreads();
    for (int i = t; i < n; i += 1024) atomicAdd(&cnt[stg[i] & 63], 1);
    __syncthreads();
    if (t < 64) {
        int v = cnt[t];
        int s = v;
        #pragma unroll
        for (int o = 1; o < 64; o <<= 1) {
            int u = __shfl_up(s, o);
            if (t >= o) s += u;
        }
        cur[t] = s - v;
        off[t] = s - v;
        if (t == 63) off[64] = s;
    }
    __syncthreads();
    for (int i = t; i < n; i += 1024) {
        int w = stg[i];
        int pos = atomicAdd(&cur[w & 63], 1);
        srt[pos] = (unsigned short)(w >> 6);
    }
    __syncthreads();

    int wv = t >> 6, lane = t & 63;
    #pragma unroll
    for (int q = 0; q < 4; ++q) {
        int ln = wv + q * 16;
        int s0 = off[ln], s1 = off[ln + 1];
        float a0x = 0.f, a0y = 0.f, a1x = 0.f, a1y = 0.f;
        float a2x = 0.f, a2y = 0.f, a3x = 0.f, a3y = 0.f;
        int i = s0;
        for (; i + 4 <= s1; i += 4) {
            int i0 = srt[i], i1 = srt[i + 1], i2 = srt[i + 2], i3 = srt[i + 3];
            unsigned u0 = xb[(size_t)i0 * 64 + lane];
            unsigned u1 = xb[(size_t)i1 * 64 + lane];
            unsigned u2 = xb[(size_t)i2 * 64 + lane];
            unsigned u3 = xb[(size_t)i3 * 64 + lane];
            a0x += __uint_as_float(u0 << 16); a0y += __uint_as_float(u0 & 0xffff0000u);
            a1x += __uint_as_float(u1 << 16); a1y += __uint_as_float(u1 & 0xffff0000u);
            a2x += __uint_as_float(u2 << 16); a2y += __uint_as_float(u2 & 0xffff0000u);
            a3x += __uint_as_float(u3 << 16); a3y += __uint_as_float(u3 & 0xffff0000u);
        }
        for (; i < s1; ++i) {
            unsigned u0 = xb[(size_t)srt[i] * 64 + lane];
            a0x += __uint_as_float(u0 << 16); a0y += __uint_as_float(u0 & 0xffff0000u);
        }
        int node = b * NPB + ln;
        if (node < NN) {
            float inv = 1.0f / fmaxf((float)(s1 - s0), 1.0f);
            float m0 = (a0x + a1x + a2x + a3x) * inv;
            float m1 = (a0y + a1y + a2y + a3y) * inv;
            meanb[(size_t)node * 64 + lane] =
                (unsigned)to_bf16(m0) | ((unsigned)to_bf16(m1) << 16);
        }
    }
}

// ---- phase 5: MFMA epilogue out = mean @ W^T + x @ B^T -------------------
// A-side: meanb (bf16) direct + x split hi/lo bf16. 3 MFMA streams.
__global__ __launch_bounds__(256) void gemm_mfma_k(const unsigned short* __restrict__ meanb,
                                                   const float* __restrict__ x,
                                                   const float* __restrict__ W,
                                                   const float* __restrict__ Bm,
                                                   float* __restrict__ out) {
    __shared__ unsigned short Wt[DD * WS];
    __shared__ unsigned short Bt[DD * WS];
    const int tid = threadIdx.x;
    #pragma unroll
    for (int it = 0; it < 16; ++it) {
        int idx = it * 256 + tid;          // float4 index into 128x128
        int n = idx >> 5;                  // W row (output col)
        int k0 = (idx & 31) * 4;           // k
        float4 w4 = ((const float4*)W)[idx];
        float4 b4 = ((const float4*)Bm)[idx];
        ushort4 wp, bp;
        wp.x = to_bf16(w4.x); wp.y = to_bf16(w4.y); wp.z = to_bf16(w4.z); wp.w = to_bf16(w4.w);
        bp.x = to_bf16(b4.x); bp.y = to_bf16(b4.y); bp.z = to_bf16(b4.z); bp.w = to_bf16(b4.w);
        *(ushort4*)&Wt[n * WS + k0] = wp;
        *(ushort4*)&Bt[n * WS + k0] = bp;
    }
    __syncthreads();

    const int wave = tid >> 6;
    const int lane = tid & 63;
    const int m = lane & 15;
    const int quad = lane >> 4;
    const int rowA = min(blockIdx.x * 64 + wave * 16 + m, NN - 1);

    f32x4 acc[8];
    #pragma unroll
    for (int nt = 0; nt < 8; ++nt) acc[nt] = (f32x4){0.f, 0.f, 0.f, 0.f};

    #pragma unroll
    for (int t = 0; t < 4; ++t) {
        const int k8 = t * 32 + quad * 8;
        short8 mf = *(const short8*)&meanb[(size_t)rowA * DD + k8];
        float xv[8];
        {
            const float4* xq = (const float4*)&x[(size_t)rowA * DD + k8];
            float4 b0 = xq[0], b1 = xq[1];
            xv[0] = b0.x; xv[1] = b0.y; xv[2] = b0.z; xv[3] = b0.w;
            xv[4] = b1.x; xv[5] = b1.y; xv[6] = b1.z; xv[7] = b1.w;
        }
        short8 xh, xl;
        #pragma unroll
        for (int j = 0; j < 8; ++j) {
            unsigned short g = to_bf16(xv[j]);
            xh[j] = (short)g;
            xl[j] = (short)to_bf16(xv[j] - __uint_as_float((unsigned)g << 16));
        }
        #pragma unroll
        for (int nt = 0; nt < 8; ++nt) {
            int nrow = nt * 16 + m;
            short8 wf = *(const short8*)&Wt[nrow * WS + k8];
            short8 bf = *(const short8*)&Bt[nrow * WS + k8];
            acc[nt] = __builtin_amdgcn_mfma_f32_16x16x32_bf16(xl, bf, acc[nt], 0, 0, 0);
            acc[nt] = __builtin_amdgcn_mfma_f32_16x16x32_bf16(mf, wf, acc[nt], 0, 0, 0);
            acc[nt] = __builtin_amdgcn_mfma_f32_16x16x32_bf16(xh, bf, acc[nt], 0, 0, 0);
        }
    }

    // C/D layout: col = lane&15, row = quad*4 + reg (verified m89/m91)
    const int rowD0 = blockIdx.x * 64 + wave * 16 + quad * 4;
    #pragma unroll
    for (int nt = 0; nt < 8; ++nt) {
        #pragma unroll
        for (int r = 0; r < 4; ++r) {
            int row = rowD0 + r;
            if (row < NN) out[(size_t)row * DD + nt * 16 + m] = acc[nt][r];
        }
    }
}

extern "C" void kernel_launch(void* const* d_in, const int* in_sizes, int n_in,
                              void* d_out, int out_size, void* d_ws, size_t ws_size,
                              hipStream_t stream) {
    const float* x  = (const float*)d_in[0];
    const int*   ei = (const int*)d_in[1];   // [2, NE] int32
    const float* W  = (const float*)d_in[2];
    const float* Bm = (const float*)d_in[3];
    float* out = (float*)d_out;

    unsigned int* meanb = (unsigned int*)d_ws;        // NN*64 uints (bf16 pairs)
    unsigned int* xb    = meanb + (size_t)NN * 64;    // NN*64 uints
    int* ebuf     = (int*)(xb + (size_t)NN * 64);     // NE
    int* gcnt     = ebuf + NE;                        // NBK
    int* gbase    = gcnt + NBK;                       // NBK+1
    int* gcursor  = gbase + NBK + 1;                  // NBK

    hipMemsetAsync(gcnt, 0, NBK * sizeof(int), stream);
    hist_k<<<NCB, 256, 0, stream>>>(ei, gcnt, x, xb);
    scan_k<<<1, 256, 0, stream>>>(gcnt, gbase, gcursor);
    scatter_k<<<NCB, 256, 0, stream>>>(ei, gcursor, ebuf);
    sortagg_k<<<NBK, 1024, 0, stream>>>(xb, ebuf, gbase, meanb);
    gemm_mfma_k<<<(NN + 63) / 64, 256, 0, stream>>>((const unsigned short*)meanb, x, W, Bm, out);
}

// Round 7
// 174.962 us; speedup vs baseline: 7.4853x; 1.2156x over previous
//
#include <hip/hip_runtime.h>
#include <hip/hip_bf16.h>

#define NN 50000
#define NE 1600000
#define DD 128
#define NPB 64                 // nodes per bucket (dst>>6)
#define NBK 782                // ceil(NN/64)
#define MAXB 2560              // bucket slab capacity (mean 2048, +11 sigma)
#define CHUNK 8192             // edges per convscatter block
#define NCB 196                // ceil(NE/CHUNK)
#define WS 136                 // gemm LDS row stride (bf16 elems): balanced banks

typedef __attribute__((ext_vector_type(8))) short short8;
typedef __attribute__((ext_vector_type(4))) float f32x4;

__device__ inline unsigned short to_bf16(float v) {
    __hip_bfloat16 h = __float2bfloat16(v);
    return __builtin_bit_cast(unsigned short, h);
}

// ---- phase 1: x->bf16 convert + bucket-sorted scatter -------------------
// Chunk staged and counting-sorted by bucket in LDS; global writes are
// lane-consecutive (coalesced). Bucket slabs reserved via gcursor atomics.
__global__ __launch_bounds__(512) void convscatter_k(const int* __restrict__ ei,
                                                     const float* __restrict__ x,
                                                     unsigned int* __restrict__ xb,
                                                     int* __restrict__ gcursor,
                                                     int* __restrict__ ebuf) {
    __shared__ int stg[CHUNK];        // 32 KB sorted chunk
    __shared__ int h[NBK];
    __shared__ int lbase[NBK];
    __shared__ int gb[NBK];
    __shared__ int hcur[NBK];
    __shared__ int sc[512];
    const int t = threadIdx.x;
    const int e0 = blockIdx.x * CHUNK;
    const int ec = min(CHUNK, NE - e0);

    for (int i = t; i < NBK; i += 512) h[i] = 0;
    __syncthreads();

    unsigned int w2[16];
    #pragma unroll
    for (int u = 0; u < 16; ++u) {
        int i = u * 512 + t;
        if (i < ec) {
            int src = ei[e0 + i];
            int dst = ei[NE + e0 + i];
            int b = dst >> 6;
            w2[u] = ((unsigned)b << 22) | ((unsigned)src << 6) | (unsigned)(dst & 63);
            atomicAdd(&h[b], 1);
        } else w2[u] = 0xFFFFFFFFu;
    }

    // independent: convert x (fp32) -> xb (packed 2x bf16 per uint)
    {
        int gid = blockIdx.x * 512 + t;
        const int total4 = NN * DD / 4;  // 1.6M float4
        for (int i = gid; i < total4; i += NCB * 512) {
            float4 v = ((const float4*)x)[i];
            unsigned int lo = (unsigned)to_bf16(v.x) | ((unsigned)to_bf16(v.y) << 16);
            unsigned int hi = (unsigned)to_bf16(v.z) | ((unsigned)to_bf16(v.w) << 16);
            ((uint2*)xb)[i] = make_uint2(lo, hi);
        }
    }
    __syncthreads();

    // block scan over NBK buckets (2 per thread) -> local bases; reserve slabs
    int b0 = 2 * t, b1 = 2 * t + 1;
    int h0 = (b0 < NBK) ? h[b0] : 0;
    int h1 = (b1 < NBK) ? h[b1] : 0;
    int v = h0 + h1;
    sc[t] = v;
    __syncthreads();
    #pragma unroll
    for (int o = 1; o < 512; o <<= 1) {
        int a = (t >= o) ? sc[t - o] : 0;
        __syncthreads();
        sc[t] += a;
        __syncthreads();
    }
    int excl = sc[t] - v;
    if (b0 < NBK) {
        lbase[b0] = excl; hcur[b0] = excl;
        gb[b0] = h0 ? b0 * MAXB + atomicAdd(&gcursor[b0], h0) : 0;
    }
    if (b1 < NBK) {
        lbase[b1] = excl + h0; hcur[b1] = excl + h0;
        gb[b1] = h1 ? b1 * MAXB + atomicAdd(&gcursor[b1], h1) : 0;
    }
    __syncthreads();

    // LDS counting sort of the chunk by bucket
    #pragma unroll
    for (int u = 0; u < 16; ++u) {
        if (w2[u] != 0xFFFFFFFFu) {
            int b = w2[u] >> 22;
            int pos = atomicAdd(&hcur[b], 1);
            stg[pos] = (int)w2[u];
        }
    }
    __syncthreads();

    // coalesced global write in sorted order
    for (int i = t; i < ec; i += 512) {
        unsigned int w = (unsigned)stg[i];
        int b = w >> 22;
        ebuf[gb[b] + (i - lbase[b])] = (int)(w & 0x3FFFFFu);
    }
}

// ---- phase 2: per-bucket node sort + aggregation ------------------------
// 512 thr = 8 waves; LDS counting sort by dstLocal -> srt, then each wave
// aggregates 8 nodes with 8-deep gather ILP from bf16 xb; writes bf16 mean.
__global__ __launch_bounds__(512) void sortagg_k(const unsigned int* __restrict__ xb,
                                                 const int* __restrict__ ebuf,
                                                 const int* __restrict__ gcursor,
                                                 unsigned int* __restrict__ meanb) {
    __shared__ int stg[MAXB];
    __shared__ unsigned short srt[MAXB];
    __shared__ int cnt[NPB], cur[NPB], off[NPB + 1];
    const int b = blockIdx.x, t = threadIdx.x;
    const int n = gcursor[b];
    const int* __restrict__ slab = ebuf + (size_t)b * MAXB;
    for (int i = t; i < n; i += 512) stg[i] = slab[i];
    if (t < NPB) cnt[t] = 0;
    __syncthreads();
    for (int i = t; i < n; i += 512) atomicAdd(&cnt[stg[i] & 63], 1);
    __syncthreads();
    if (t < 64) {
        int v = cnt[t];
        int s = v;
        #pragma unroll
        for (int o = 1; o < 64; o <<= 1) {
            int u = __shfl_up(s, o);
            if (t >= o) s += u;
        }
        cur[t] = s - v;
        off[t] = s - v;
        if (t == 63) off[64] = s;
    }
    __syncthreads();
    for (int i = t; i < n; i += 512) {
        int w = stg[i];
        int pos = atomicAdd(&cur[w & 63], 1);
        srt[pos] = (unsigned short)(w >> 6);
    }
    __syncthreads();

    const int wv = t >> 6, lane = t & 63;
    #pragma unroll
    for (int q = 0; q < 8; ++q) {
        int ln = wv + q * 8;                 // interleaved for degree balance
        int s0 = off[ln], s1 = off[ln + 1];
        float ax[8], ay[8];
        #pragma unroll
        for (int k = 0; k < 8; ++k) { ax[k] = 0.f; ay[k] = 0.f; }
        int i = s0;
        for (; i + 8 <= s1; i += 8) {
            unsigned int u[8];
            #pragma unroll
            for (int k = 0; k < 8; ++k) u[k] = xb[(size_t)srt[i + k] * 64 + lane];
            #pragma unroll
            for (int k = 0; k < 8; ++k) {
                ax[k] += __uint_as_float(u[k] << 16);
                ay[k] += __uint_as_float(u[k] & 0xffff0000u);
            }
        }
        for (; i < s1; ++i) {
            unsigned int u0 = xb[(size_t)srt[i] * 64 + lane];
            ax[0] += __uint_as_float(u0 << 16);
            ay[0] += __uint_as_float(u0 & 0xffff0000u);
        }
        int node = b * NPB + ln;
        if (node < NN) {
            float sx = ((ax[0] + ax[1]) + (ax[2] + ax[3])) + ((ax[4] + ax[5]) + (ax[6] + ax[7]));
            float sy = ((ay[0] + ay[1]) + (ay[2] + ay[3])) + ((ay[4] + ay[5]) + (ay[6] + ay[7]));
            float inv = 1.0f / fmaxf((float)(s1 - s0), 1.0f);
            meanb[(size_t)node * 64 + lane] =
                (unsigned)to_bf16(sx * inv) | ((unsigned)to_bf16(sy * inv) << 16);
        }
    }
}

// ---- phase 3: MFMA epilogue out = mean @ W^T + x @ B^T -------------------
__global__ __launch_bounds__(256) void gemm_mfma_k(const unsigned short* __restrict__ meanb,
                                                   const float* __restrict__ x,
                                                   const float* __restrict__ W,
                                                   const float* __restrict__ Bm,
                                                   float* __restrict__ out) {
    __shared__ unsigned short Wt[DD * WS];
    __shared__ unsigned short Bt[DD * WS];
    const int tid = threadIdx.x;
    #pragma unroll
    for (int it = 0; it < 16; ++it) {
        int idx = it * 256 + tid;
        int n = idx >> 5;
        int k0 = (idx & 31) * 4;
        float4 w4 = ((const float4*)W)[idx];
        float4 b4 = ((const float4*)Bm)[idx];
        ushort4 wp, bp;
        wp.x = to_bf16(w4.x); wp.y = to_bf16(w4.y); wp.z = to_bf16(w4.z); wp.w = to_bf16(w4.w);
        bp.x = to_bf16(b4.x); bp.y = to_bf16(b4.y); bp.z = to_bf16(b4.z); bp.w = to_bf16(b4.w);
        *(ushort4*)&Wt[n * WS + k0] = wp;
        *(ushort4*)&Bt[n * WS + k0] = bp;
    }
    __syncthreads();

    const int wave = tid >> 6;
    const int lane = tid & 63;
    const int m = lane & 15;
    const int quad = lane >> 4;
    const int rowA = min(blockIdx.x * 64 + wave * 16 + m, NN - 1);

    f32x4 acc[8];
    #pragma unroll
    for (int nt = 0; nt < 8; ++nt) acc[nt] = (f32x4){0.f, 0.f, 0.f, 0.f};

    #pragma unroll
    for (int t = 0; t < 4; ++t) {
        const int k8 = t * 32 + quad * 8;
        short8 mf = *(const short8*)&meanb[(size_t)rowA * DD + k8];
        float xv[8];
        {
            const float4* xq = (const float4*)&x[(size_t)rowA * DD + k8];
            float4 b0 = xq[0], b1 = xq[1];
            xv[0] = b0.x; xv[1] = b0.y; xv[2] = b0.z; xv[3] = b0.w;
            xv[4] = b1.x; xv[5] = b1.y; xv[6] = b1.z; xv[7] = b1.w;
        }
        short8 xh, xl;
        #pragma unroll
        for (int j = 0; j < 8; ++j) {
            unsigned short g = to_bf16(xv[j]);
            xh[j] = (short)g;
            xl[j] = (short)to_bf16(xv[j] - __uint_as_float((unsigned)g << 16));
        }
        #pragma unroll
        for (int nt = 0; nt < 8; ++nt) {
            int nrow = nt * 16 + m;
            short8 wf = *(const short8*)&Wt[nrow * WS + k8];
            short8 bf = *(const short8*)&Bt[nrow * WS + k8];
            acc[nt] = __builtin_amdgcn_mfma_f32_16x16x32_bf16(xl, bf, acc[nt], 0, 0, 0);
            acc[nt] = __builtin_amdgcn_mfma_f32_16x16x32_bf16(mf, wf, acc[nt], 0, 0, 0);
            acc[nt] = __builtin_amdgcn_mfma_f32_16x16x32_bf16(xh, bf, acc[nt], 0, 0, 0);
        }
    }

    // C/D layout: col = lane&15, row = quad*4 + reg (verified m89/m91)
    const int rowD0 = blockIdx.x * 64 + wave * 16 + quad * 4;
    #pragma unroll
    for (int nt = 0; nt < 8; ++nt) {
        #pragma unroll
        for (int r = 0; r < 4; ++r) {
            int row = rowD0 + r;
            if (row < NN) out[(size_t)row * DD + nt * 16 + m] = acc[nt][r];
        }
    }
}

extern "C" void kernel_launch(void* const* d_in, const int* in_sizes, int n_in,
                              void* d_out, int out_size, void* d_ws, size_t ws_size,
                              hipStream_t stream) {
    const float* x  = (const float*)d_in[0];
    const int*   ei = (const int*)d_in[1];   // [2, NE] int32
    const float* W  = (const float*)d_in[2];
    const float* Bm = (const float*)d_in[3];
    float* out = (float*)d_out;

    unsigned int* meanb = (unsigned int*)d_ws;          // NN*64 uints
    unsigned int* xb    = meanb + (size_t)NN * 64;      // NN*64 uints
    int* ebuf     = (int*)(xb + (size_t)NN * 64);       // NBK*MAXB
    int* gcursor  = ebuf + (size_t)NBK * MAXB;          // NBK

    hipMemsetAsync(gcursor, 0, NBK * sizeof(int), stream);
    convscatter_k<<<NCB, 512, 0, stream>>>(ei, x, xb, gcursor, ebuf);
    sortagg_k<<<NBK, 512, 0, stream>>>(xb, ebuf, gcursor, meanb);
    gemm_mfma_k<<<(NN + 63) / 64, 256, 0, stream>>>((const unsigned short*)meanb, x, W, Bm, out);
}

// Round 8
// 154.383 us; speedup vs baseline: 8.4831x; 1.1333x over previous
//
#include <hip/hip_runtime.h>
#include <hip/hip_bf16.h>

#define NN 50000
#define NE 1600000
#define DD 128
#define NPB 64                 // nodes per bucket (dst>>6)
#define NBK 782                // ceil(NN/64)
#define MAXB 2560              // bucket slab capacity (mean 2048, +11 sigma)
#define CHUNK 6144             // edges per convscatter block
#define NCB 261                // ceil(NE/CHUNK)
#define WS 136                 // gemm LDS row stride (bf16 elems): balanced banks

typedef __attribute__((ext_vector_type(8))) short short8;
typedef __attribute__((ext_vector_type(4))) float f32x4;

__device__ inline unsigned short to_bf16(float v) {
    __hip_bfloat16 h = __float2bfloat16(v);
    return __builtin_bit_cast(unsigned short, h);
}

// ---- phase 1: x->fp8 convert + bucket-sorted scatter --------------------
// 1024 thr, 261 blocks. Chunk staged + counting-sorted by bucket in LDS;
// global ebuf writes are lane-consecutive. Slabs reserved via gcursor.
__global__ __launch_bounds__(1024) void convscatter_k(const int* __restrict__ ei,
                                                      const float* __restrict__ x,
                                                      unsigned int* __restrict__ xb,
                                                      int* __restrict__ gcursor,
                                                      int* __restrict__ ebuf) {
    __shared__ int stg[CHUNK];        // 24 KB
    __shared__ int h[NBK];
    __shared__ int lbase[NBK];
    __shared__ int gb[NBK];
    __shared__ int hcur[NBK];
    __shared__ int sc[1024];
    const int t = threadIdx.x;
    const int e0 = blockIdx.x * CHUNK;
    const int ec = min(CHUNK, NE - e0);

    for (int i = t; i < NBK; i += 1024) h[i] = 0;
    __syncthreads();

    unsigned int w2[6];
    #pragma unroll
    for (int u = 0; u < 6; ++u) {
        int i = u * 1024 + t;
        if (i < ec) {
            int src = ei[e0 + i];
            int dst = ei[NE + e0 + i];
            int b = dst >> 6;
            w2[u] = ((unsigned)b << 22) | ((unsigned)src << 6) | (unsigned)(dst & 63);
            atomicAdd(&h[b], 1);
        } else w2[u] = 0xFFFFFFFFu;
    }

    // independent: convert x (fp32) -> xb (packed 4x fp8-e4m3 per uint)
    {
        int gid = blockIdx.x * 1024 + t;
        const int total4 = NN * DD / 4;  // 1.6M float4 -> 1.6M uints
        for (int i = gid; i < total4; i += NCB * 1024) {
            float4 v = ((const float4*)x)[i];
            int p = __builtin_amdgcn_cvt_pk_fp8_f32(v.x, v.y, 0, false);
            p = __builtin_amdgcn_cvt_pk_fp8_f32(v.z, v.w, p, true);
            xb[i] = (unsigned)p;
        }
    }
    __syncthreads();

    // block scan over NBK buckets (1 per thread) -> local bases; reserve slabs
    int v = (t < NBK) ? h[t] : 0;
    sc[t] = v;
    __syncthreads();
    #pragma unroll
    for (int o = 1; o < 1024; o <<= 1) {
        int a = (t >= o) ? sc[t - o] : 0;
        __syncthreads();
        sc[t] += a;
        __syncthreads();
    }
    int excl = sc[t] - v;
    if (t < NBK) {
        lbase[t] = excl;
        hcur[t] = excl;
        gb[t] = v ? t * MAXB + atomicAdd(&gcursor[t], v) : 0;
    }
    __syncthreads();

    // LDS counting sort of the chunk by bucket
    #pragma unroll
    for (int u = 0; u < 6; ++u) {
        if (w2[u] != 0xFFFFFFFFu) {
            int b = w2[u] >> 22;
            int pos = atomicAdd(&hcur[b], 1);
            stg[pos] = (int)w2[u];
        }
    }
    __syncthreads();

    // coalesced global write in sorted order
    for (int i = t; i < ec; i += 1024) {
        unsigned int w = (unsigned)stg[i];
        int b = w >> 22;
        ebuf[gb[b] + (i - lbase[b])] = (int)(w & 0x3FFFFFu);
    }
}

// ---- phase 2: per-bucket node sort + fp8 aggregation --------------------
// 512 thr = 8 waves. LDS counting sort by dstLocal -> srt; then each wave:
// 2 edges at a time (half-wave = one 128B fp8 row), 4 features/lane,
// 8-pair ILP, cross-half shfl reduce, bf16 mean write.
__global__ __launch_bounds__(512) void sortagg_k(const unsigned int* __restrict__ xb,
                                                 const int* __restrict__ ebuf,
                                                 const int* __restrict__ gcursor,
                                                 unsigned int* __restrict__ meanb) {
    __shared__ int stg[MAXB];
    __shared__ unsigned short srt[MAXB];
    __shared__ int cnt[NPB], cur[NPB], off[NPB + 1];
    const int b = blockIdx.x, t = threadIdx.x;
    const int n = gcursor[b];
    const int* __restrict__ slab = ebuf + (size_t)b * MAXB;
    for (int i = t; i < n; i += 512) stg[i] = slab[i];
    if (t < NPB) cnt[t] = 0;
    __syncthreads();
    for (int i = t; i < n; i += 512) atomicAdd(&cnt[stg[i] & 63], 1);
    __syncthreads();
    if (t < 64) {
        int v = cnt[t];
        int s = v;
        #pragma unroll
        for (int o = 1; o < 64; o <<= 1) {
            int u = __shfl_up(s, o);
            if (t >= o) s += u;
        }
        cur[t] = s - v;
        off[t] = s - v;
        if (t == 63) off[64] = s;
    }
    __syncthreads();
    for (int i = t; i < n; i += 512) {
        int w = stg[i];
        int pos = atomicAdd(&cur[w & 63], 1);
        srt[pos] = (unsigned short)(w >> 6);
    }
    __syncthreads();

    const int wv = t >> 6, lane = t & 63;
    const int half = lane >> 5, il = lane & 31;
    #pragma unroll
    for (int q = 0; q < 8; ++q) {
        int ln = wv + q * 8;                 // interleaved for degree balance
        int s0 = off[ln], s1 = off[ln + 1];
        float a0 = 0.f, a1 = 0.f, a2 = 0.f, a3 = 0.f;
        int i = s0;
        for (; i + 16 <= s1; i += 16) {
            unsigned int u[8];
            #pragma unroll
            for (int k = 0; k < 8; ++k)
                u[k] = xb[(size_t)srt[i + 2 * k + half] * 32 + il];
            #pragma unroll
            for (int k = 0; k < 8; ++k) {
                auto lo = __builtin_amdgcn_cvt_pk_f32_fp8((int)u[k], false);
                auto hi = __builtin_amdgcn_cvt_pk_f32_fp8((int)u[k], true);
                a0 += lo[0]; a1 += lo[1]; a2 += hi[0]; a3 += hi[1];
            }
        }
        for (; i < s1; i += 2) {
            int e = i + half;
            unsigned int u = (e < s1) ? xb[(size_t)srt[e] * 32 + il] : 0u;
            auto lo = __builtin_amdgcn_cvt_pk_f32_fp8((int)u, false);
            auto hi = __builtin_amdgcn_cvt_pk_f32_fp8((int)u, true);
            a0 += lo[0]; a1 += lo[1]; a2 += hi[0]; a3 += hi[1];
        }
        // cross-half reduce (edge-parallel halves hold same features)
        a0 += __shfl_xor(a0, 32);
        a1 += __shfl_xor(a1, 32);
        a2 += __shfl_xor(a2, 32);
        a3 += __shfl_xor(a3, 32);
        int node = b * NPB + ln;
        if (half == 0 && node < NN) {
            float inv = 1.0f / fmaxf((float)(s1 - s0), 1.0f);
            unsigned lo = (unsigned)to_bf16(a0 * inv) | ((unsigned)to_bf16(a1 * inv) << 16);
            unsigned hi = (unsigned)to_bf16(a2 * inv) | ((unsigned)to_bf16(a3 * inv) << 16);
            ((uint2*)meanb)[(size_t)node * 32 + il] = make_uint2(lo, hi);
        }
    }
}

// ---- phase 3: MFMA epilogue out = mean @ W^T + x @ B^T -------------------
__global__ __launch_bounds__(256) void gemm_mfma_k(const unsigned short* __restrict__ meanb,
                                                   const float* __restrict__ x,
                                                   const float* __restrict__ W,
                                                   const float* __restrict__ Bm,
                                                   float* __restrict__ out) {
    __shared__ unsigned short Wt[DD * WS];
    __shared__ unsigned short Bt[DD * WS];
    const int tid = threadIdx.x;
    #pragma unroll
    for (int it = 0; it < 16; ++it) {
        int idx = it * 256 + tid;
        int n = idx >> 5;
        int k0 = (idx & 31) * 4;
        float4 w4 = ((const float4*)W)[idx];
        float4 b4 = ((const float4*)Bm)[idx];
        ushort4 wp, bp;
        wp.x = to_bf16(w4.x); wp.y = to_bf16(w4.y); wp.z = to_bf16(w4.z); wp.w = to_bf16(w4.w);
        bp.x = to_bf16(b4.x); bp.y = to_bf16(b4.y); bp.z = to_bf16(b4.z); bp.w = to_bf16(b4.w);
        *(ushort4*)&Wt[n * WS + k0] = wp;
        *(ushort4*)&Bt[n * WS + k0] = bp;
    }
    __syncthreads();

    const int wave = tid >> 6;
    const int lane = tid & 63;
    const int m = lane & 15;
    const int quad = lane >> 4;
    const int rowA = min(blockIdx.x * 64 + wave * 16 + m, NN - 1);

    f32x4 acc[8];
    #pragma unroll
    for (int nt = 0; nt < 8; ++nt) acc[nt] = (f32x4){0.f, 0.f, 0.f, 0.f};

    #pragma unroll
    for (int t = 0; t < 4; ++t) {
        const int k8 = t * 32 + quad * 8;
        short8 mf = *(const short8*)&meanb[(size_t)rowA * DD + k8];
        float xv[8];
        {
            const float4* xq = (const float4*)&x[(size_t)rowA * DD + k8];
            float4 b0 = xq[0], b1 = xq[1];
            xv[0] = b0.x; xv[1] = b0.y; xv[2] = b0.z; xv[3] = b0.w;
            xv[4] = b1.x; xv[5] = b1.y; xv[6] = b1.z; xv[7] = b1.w;
        }
        short8 xh, xl;
        #pragma unroll
        for (int j = 0; j < 8; ++j) {
            unsigned short g = to_bf16(xv[j]);
            xh[j] = (short)g;
            xl[j] = (short)to_bf16(xv[j] - __uint_as_float((unsigned)g << 16));
        }
        #pragma unroll
        for (int nt = 0; nt < 8; ++nt) {
            int nrow = nt * 16 + m;
            short8 wf = *(const short8*)&Wt[nrow * WS + k8];
            short8 bf = *(const short8*)&Bt[nrow * WS + k8];
            acc[nt] = __builtin_amdgcn_mfma_f32_16x16x32_bf16(xl, bf, acc[nt], 0, 0, 0);
            acc[nt] = __builtin_amdgcn_mfma_f32_16x16x32_bf16(mf, wf, acc[nt], 0, 0, 0);
            acc[nt] = __builtin_amdgcn_mfma_f32_16x16x32_bf16(xh, bf, acc[nt], 0, 0, 0);
        }
    }

    // C/D layout: col = lane&15, row = quad*4 + reg (verified m89/m91)
    const int rowD0 = blockIdx.x * 64 + wave * 16 + quad * 4;
    #pragma unroll
    for (int nt = 0; nt < 8; ++nt) {
        #pragma unroll
        for (int r = 0; r < 4; ++r) {
            int row = rowD0 + r;
            if (row < NN) out[(size_t)row * DD + nt * 16 + m] = acc[nt][r];
        }
    }
}

extern "C" void kernel_launch(void* const* d_in, const int* in_sizes, int n_in,
                              void* d_out, int out_size, void* d_ws, size_t ws_size,
                              hipStream_t stream) {
    const float* x  = (const float*)d_in[0];
    const int*   ei = (const int*)d_in[1];   // [2, NE] int32
    const float* W  = (const float*)d_in[2];
    const float* Bm = (const float*)d_in[3];
    float* out = (float*)d_out;

    unsigned int* meanb = (unsigned int*)d_ws;          // NN*64 uints (bf16 pairs)
    unsigned int* xb    = meanb + (size_t)NN * 64;      // NN*32 uints (fp8 quads)
    int* ebuf     = (int*)(xb + (size_t)NN * 32);       // NBK*MAXB
    int* gcursor  = ebuf + (size_t)NBK * MAXB;          // NBK

    hipMemsetAsync(gcursor, 0, NBK * sizeof(int), stream);
    convscatter_k<<<NCB, 1024, 0, stream>>>(ei, x, xb, gcursor, ebuf);
    sortagg_k<<<NBK, 512, 0, stream>>>(xb, ebuf, gcursor, meanb);
    gemm_mfma_k<<<(NN + 63) / 64, 256, 0, stream>>>((const unsigned short*)meanb, x, W, Bm, out);
}

// Round 9
// 153.983 us; speedup vs baseline: 8.5051x; 1.0026x over previous
//
#include <hip/hip_runtime.h>
#include <hip/hip_bf16.h>

#define NN 50000
#define NE 1600000
#define DD 128
#define NPB 64                 // nodes per bucket (dst>>6)
#define NBK 782                // ceil(NN/64)
#define MAXB 2560              // bucket slab capacity (mean 2048, +11 sigma)
#define CHUNK 6144             // edges per convscatter block
#define NCB 261                // ceil(NE/CHUNK)
#define WS 136                 // gemm LDS row stride (bf16 elems): balanced banks

typedef __attribute__((ext_vector_type(8))) short short8;
typedef __attribute__((ext_vector_type(4))) float f32x4;

__device__ inline unsigned short to_bf16(float v) {
    __hip_bfloat16 h = __float2bfloat16(v);
    return __builtin_bit_cast(unsigned short, h);
}

// ---- phase 1: x->fp8 convert + bucket-sorted scatter --------------------
// 1024 thr, 261 blocks. Chunk staged + counting-sorted by bucket in LDS;
// global ebuf writes lane-consecutive. Hierarchical wave scan (2 barriers).
__global__ __launch_bounds__(1024) void convscatter_k(const int* __restrict__ ei,
                                                      const float* __restrict__ x,
                                                      unsigned int* __restrict__ xb,
                                                      int* __restrict__ gcursor,
                                                      int* __restrict__ ebuf) {
    __shared__ int stg[CHUNK];        // 24 KB
    __shared__ int h[NBK];
    __shared__ int lbase[NBK];
    __shared__ int gb[NBK];
    __shared__ int hcur[NBK];
    __shared__ int wsum[16], wbase[16];
    const int t = threadIdx.x;
    const int lane = t & 63, wv = t >> 6;
    const int e0 = blockIdx.x * CHUNK;
    const int ec = min(CHUNK, NE - e0);

    for (int i = t; i < NBK; i += 1024) h[i] = 0;
    __syncthreads();

    unsigned int w2[6];
    #pragma unroll
    for (int u = 0; u < 6; ++u) {
        int i = u * 1024 + t;
        if (i < ec) {
            int src = ei[e0 + i];
            int dst = ei[NE + e0 + i];
            int b = dst >> 6;
            w2[u] = ((unsigned)b << 22) | ((unsigned)src << 6) | (unsigned)(dst & 63);
            atomicAdd(&h[b], 1);
        } else w2[u] = 0xFFFFFFFFu;
    }

    // independent: convert x (fp32) -> xb (packed 4x fp8-e4m3 per uint)
    {
        int gid = blockIdx.x * 1024 + t;
        const int total4 = NN * DD / 4;  // 1.6M float4 -> 1.6M uints
        for (int i = gid; i < total4; i += NCB * 1024) {
            float4 v = ((const float4*)x)[i];
            int p = __builtin_amdgcn_cvt_pk_fp8_f32(v.x, v.y, 0, false);
            p = __builtin_amdgcn_cvt_pk_fp8_f32(v.z, v.w, p, true);
            xb[i] = (unsigned)p;
        }
    }
    __syncthreads();

    // hierarchical scan over NBK buckets (1 per thread, 2 barriers)
    int v = (t < NBK) ? h[t] : 0;
    int s = v;
    #pragma unroll
    for (int o = 1; o < 64; o <<= 1) {
        int u = __shfl_up(s, o);
        if (lane >= o) s += u;
    }
    if (lane == 63) wsum[wv] = s;
    __syncthreads();
    if (wv == 0 && lane < 16) {
        int bv = wsum[lane];
        int bs = bv;
        #pragma unroll
        for (int o = 1; o < 16; o <<= 1) {
            int u = __shfl_up(bs, o);
            if (lane >= o) bs += u;
        }
        wbase[lane] = bs - bv;
    }
    __syncthreads();
    if (t < NBK) {
        int excl = s - v + wbase[wv];
        lbase[t] = excl;
        hcur[t] = excl;
        gb[t] = v ? t * MAXB + atomicAdd(&gcursor[t], v) : 0;
    }
    __syncthreads();

    // LDS counting sort of the chunk by bucket
    #pragma unroll
    for (int u = 0; u < 6; ++u) {
        if (w2[u] != 0xFFFFFFFFu) {
            int b = w2[u] >> 22;
            int pos = atomicAdd(&hcur[b], 1);
            stg[pos] = (int)w2[u];
        }
    }
    __syncthreads();

    // coalesced global write in sorted order
    for (int i = t; i < ec; i += 1024) {
        unsigned int w = (unsigned)stg[i];
        int b = w >> 22;
        ebuf[gb[b] + (i - lbase[b])] = (int)(w & 0x3FFFFFu);
    }
}

// ---- phase 2: per-bucket node sort + fp8 aggregation --------------------
// 512 thr = 8 waves. Per-wave split histograms (8x fewer LDS-atomic hits),
// then 16-deep gather ILP: 32 edges in flight per wave per round.
__global__ __launch_bounds__(512) void sortagg_k(const unsigned int* __restrict__ xb,
                                                 const int* __restrict__ ebuf,
                                                 const int* __restrict__ gcursor,
                                                 unsigned int* __restrict__ meanb) {
    __shared__ int stg[MAXB];
    __shared__ unsigned short srt[MAXB];
    __shared__ int cnt8[8][NPB];
    __shared__ int cur[NPB], off[NPB + 1];
    const int b = blockIdx.x, t = threadIdx.x;
    const int wv = t >> 6, lane = t & 63;
    const int n = gcursor[b];
    const int* __restrict__ slab = ebuf + (size_t)b * MAXB;
    for (int i = t; i < n; i += 512) stg[i] = slab[i];
    if (lane < NPB) cnt8[wv][lane] = 0;
    __syncthreads();
    for (int i = t; i < n; i += 512) atomicAdd(&cnt8[wv][stg[i] & 63], 1);
    __syncthreads();
    if (t < 64) {
        int v = 0;
        #pragma unroll
        for (int w = 0; w < 8; ++w) v += cnt8[w][t];
        int s = v;
        #pragma unroll
        for (int o = 1; o < 64; o <<= 1) {
            int u = __shfl_up(s, o);
            if (t >= o) s += u;
        }
        cur[t] = s - v;
        off[t] = s - v;
        if (t == 63) off[64] = s;
    }
    __syncthreads();
    for (int i = t; i < n; i += 512) {
        int w = stg[i];
        int pos = atomicAdd(&cur[w & 63], 1);
        srt[pos] = (unsigned short)(w >> 6);
    }
    __syncthreads();

    const int half = lane >> 5, il = lane & 31;
    #pragma unroll
    for (int q = 0; q < 8; ++q) {
        int ln = wv + q * 8;                 // interleaved for degree balance
        int s0 = off[ln], s1 = off[ln + 1];
        float a0 = 0.f, a1 = 0.f, a2 = 0.f, a3 = 0.f;
        int i = s0;
        for (; i + 32 <= s1; i += 32) {      // 16 outstanding loads
            unsigned int u[16];
            #pragma unroll
            for (int k = 0; k < 16; ++k)
                u[k] = xb[(size_t)srt[i + 2 * k + half] * 32 + il];
            #pragma unroll
            for (int k = 0; k < 16; ++k) {
                auto lo = __builtin_amdgcn_cvt_pk_f32_fp8((int)u[k], false);
                auto hi = __builtin_amdgcn_cvt_pk_f32_fp8((int)u[k], true);
                a0 += lo[0]; a1 += lo[1]; a2 += hi[0]; a3 += hi[1];
            }
        }
        if (i + 16 <= s1) {
            unsigned int u[8];
            #pragma unroll
            for (int k = 0; k < 8; ++k)
                u[k] = xb[(size_t)srt[i + 2 * k + half] * 32 + il];
            #pragma unroll
            for (int k = 0; k < 8; ++k) {
                auto lo = __builtin_amdgcn_cvt_pk_f32_fp8((int)u[k], false);
                auto hi = __builtin_amdgcn_cvt_pk_f32_fp8((int)u[k], true);
                a0 += lo[0]; a1 += lo[1]; a2 += hi[0]; a3 += hi[1];
            }
            i += 16;
        }
        for (; i < s1; i += 2) {
            int e = i + half;
            unsigned int u = (e < s1) ? xb[(size_t)srt[e] * 32 + il] : 0u;
            auto lo = __builtin_amdgcn_cvt_pk_f32_fp8((int)u, false);
            auto hi = __builtin_amdgcn_cvt_pk_f32_fp8((int)u, true);
            a0 += lo[0]; a1 += lo[1]; a2 += hi[0]; a3 += hi[1];
        }
        // cross-half reduce (edge-parallel halves hold same features)
        a0 += __shfl_xor(a0, 32);
        a1 += __shfl_xor(a1, 32);
        a2 += __shfl_xor(a2, 32);
        a3 += __shfl_xor(a3, 32);
        int node = b * NPB + ln;
        if (half == 0 && node < NN) {
            float inv = 1.0f / fmaxf((float)(s1 - s0), 1.0f);
            unsigned lo = (unsigned)to_bf16(a0 * inv) | ((unsigned)to_bf16(a1 * inv) << 16);
            unsigned hi = (unsigned)to_bf16(a2 * inv) | ((unsigned)to_bf16(a3 * inv) << 16);
            ((uint2*)meanb)[(size_t)node * 32 + il] = make_uint2(lo, hi);
        }
    }
}

// ---- phase 3: MFMA epilogue out = mean @ W^T + x @ B^T -------------------
__global__ __launch_bounds__(256) void gemm_mfma_k(const unsigned short* __restrict__ meanb,
                                                   const float* __restrict__ x,
                                                   const float* __restrict__ W,
                                                   const float* __restrict__ Bm,
                                                   float* __restrict__ out) {
    __shared__ unsigned short Wt[DD * WS];
    __shared__ unsigned short Bt[DD * WS];
    const int tid = threadIdx.x;
    #pragma unroll
    for (int it = 0; it < 16; ++it) {
        int idx = it * 256 + tid;
        int n = idx >> 5;
        int k0 = (idx & 31) * 4;
        float4 w4 = ((const float4*)W)[idx];
        float4 b4 = ((const float4*)Bm)[idx];
        ushort4 wp, bp;
        wp.x = to_bf16(w4.x); wp.y = to_bf16(w4.y); wp.z = to_bf16(w4.z); wp.w = to_bf16(w4.w);
        bp.x = to_bf16(b4.x); bp.y = to_bf16(b4.y); bp.z = to_bf16(b4.z); bp.w = to_bf16(b4.w);
        *(ushort4*)&Wt[n * WS + k0] = wp;
        *(ushort4*)&Bt[n * WS + k0] = bp;
    }
    __syncthreads();

    const int wave = tid >> 6;
    const int lane = tid & 63;
    const int m = lane & 15;
    const int quad = lane >> 4;
    const int rowA = min(blockIdx.x * 64 + wave * 16 + m, NN - 1);

    f32x4 acc[8];
    #pragma unroll
    for (int nt = 0; nt < 8; ++nt) acc[nt] = (f32x4){0.f, 0.f, 0.f, 0.f};

    #pragma unroll
    for (int t = 0; t < 4; ++t) {
        const int k8 = t * 32 + quad * 8;
        short8 mf = *(const short8*)&meanb[(size_t)rowA * DD + k8];
        float xv[8];
        {
            const float4* xq = (const float4*)&x[(size_t)rowA * DD + k8];
            float4 b0 = xq[0], b1 = xq[1];
            xv[0] = b0.x; xv[1] = b0.y; xv[2] = b0.z; xv[3] = b0.w;
            xv[4] = b1.x; xv[5] = b1.y; xv[6] = b1.z; xv[7] = b1.w;
        }
        short8 xh, xl;
        #pragma unroll
        for (int j = 0; j < 8; ++j) {
            unsigned short g = to_bf16(xv[j]);
            xh[j] = (short)g;
            xl[j] = (short)to_bf16(xv[j] - __uint_as_float((unsigned)g << 16));
        }
        #pragma unroll
        for (int nt = 0; nt < 8; ++nt) {
            int nrow = nt * 16 + m;
            short8 wf = *(const short8*)&Wt[nrow * WS + k8];
            short8 bf = *(const short8*)&Bt[nrow * WS + k8];
            acc[nt] = __builtin_amdgcn_mfma_f32_16x16x32_bf16(xl, bf, acc[nt], 0, 0, 0);
            acc[nt] = __builtin_amdgcn_mfma_f32_16x16x32_bf16(mf, wf, acc[nt], 0, 0, 0);
            acc[nt] = __builtin_amdgcn_mfma_f32_16x16x32_bf16(xh, bf, acc[nt], 0, 0, 0);
        }
    }

    // C/D layout: col = lane&15, row = quad*4 + reg (verified m89/m91)
    const int rowD0 = blockIdx.x * 64 + wave * 16 + quad * 4;
    #pragma unroll
    for (int nt = 0; nt < 8; ++nt) {
        #pragma unroll
        for (int r = 0; r < 4; ++r) {
            int row = rowD0 + r;
            if (row < NN) out[(size_t)row * DD + nt * 16 + m] = acc[nt][r];
        }
    }
}

extern "C" void kernel_launch(void* const* d_in, const int* in_sizes, int n_in,
                              void* d_out, int out_size, void* d_ws, size_t ws_size,
                              hipStream_t stream) {
    const float* x  = (const float*)d_in[0];
    const int*   ei = (const int*)d_in[1];   // [2, NE] int32
    const float* W  = (const float*)d_in[2];
    const float* Bm = (const float*)d_in[3];
    float* out = (float*)d_out;

    unsigned int* meanb = (unsigned int*)d_ws;          // NN*64 uints (bf16 pairs)
    unsigned int* xb    = meanb + (size_t)NN * 64;      // NN*32 uints (fp8 quads)
    int* ebuf     = (int*)(xb + (size_t)NN * 32);       // NBK*MAXB
    int* gcursor  = ebuf + (size_t)NBK * MAXB;          // NBK

    hipMemsetAsync(gcursor, 0, NBK * sizeof(int), stream);
    convscatter_k<<<NCB, 1024, 0, stream>>>(ei, x, xb, gcursor, ebuf);
    sortagg_k<<<NBK, 512, 0, stream>>>(xb, ebuf, gcursor, meanb);
    gemm_mfma_k<<<(NN + 63) / 64, 256, 0, stream>>>((const unsigned short*)meanb, x, W, Bm, out);
}